// Round 1
// baseline (484.676 us; speedup 1.0000x reference)
//
#include <hip/hip_runtime.h>
#include <math.h>

#define B_SZ 4096
#define F_SZ 512
#define J_SZ 16
#define M_SZ 64
#define U_SZ 512
#define P_SZ (J_SZ * M_SZ)   // 1024

// K(x,y) = exp(-||x-y||^2 / (2*sigma^2)), sigma=0.5 -> exp(-2*sqdist)
#define GAUSS_COEF (-2.0f)

// ---------------------------------------------------------------------------
// h2[b] = sum_f h[b,f]^2   (one wave per row)
// ---------------------------------------------------------------------------
__global__ __launch_bounds__(64) void h2_kernel(const float* __restrict__ h,
                                                float* __restrict__ h2) {
    int b = blockIdx.x;
    int lane = threadIdx.x;
    const float4* row = (const float4*)(h + (size_t)b * F_SZ);
    float s = 0.f;
    for (int i = lane; i < F_SZ / 4; i += 64) {
        float4 v = row[i];
        s += v.x * v.x + v.y * v.y + v.z * v.z + v.w * v.w;
    }
    for (int off = 32; off; off >>= 1) s += __shfl_down(s, off);
    if (lane == 0) h2[b] = s;
}

// ---------------------------------------------------------------------------
// d2[j,m] = sum_f dom[j,m,f]^2 ;  kdd[j] = mean_{m,n} exp(-2*||d_m-d_n||^2)
// one block per j
// ---------------------------------------------------------------------------
__global__ __launch_bounds__(256) void dom_kernel(const float* __restrict__ dom,
                                                  float* __restrict__ d2,
                                                  float* __restrict__ kdd) {
    int j = blockIdx.x;
    int tid = threadIdx.x;
    const float* base = dom + (size_t)j * M_SZ * F_SZ;

    if (tid < M_SZ) {
        const float4* r = (const float4*)(base + (size_t)tid * F_SZ);
        float s = 0.f;
        for (int i = 0; i < F_SZ / 4; ++i) {
            float4 v = r[i];
            s += v.x * v.x + v.y * v.y + v.z * v.z + v.w * v.w;
        }
        d2[j * M_SZ + tid] = s;
    }

    float acc = 0.f;
    for (int pp = tid; pp < M_SZ * M_SZ; pp += 256) {
        int m = pp >> 6, n = pp & 63;
        const float4* rm = (const float4*)(base + (size_t)m * F_SZ);
        const float4* rn = (const float4*)(base + (size_t)n * F_SZ);
        float sq = 0.f;
        for (int i = 0; i < F_SZ / 4; ++i) {
            float4 a = rm[i], c = rn[i];
            float dx = a.x - c.x, dy = a.y - c.y, dz = a.z - c.z, dw = a.w - c.w;
            sq += dx * dx + dy * dy + dz * dz + dw * dw;
        }
        acc += __expf(GAUSS_COEF * sq);
    }
    __shared__ float red[256];
    red[tid] = acc;
    __syncthreads();
    for (int off = 128; off; off >>= 1) {
        if (tid < off) red[tid] += red[tid + off];
        __syncthreads();
    }
    if (tid == 0) kdd[j] = red[0] * (1.f / (M_SZ * M_SZ));
}

// ---------------------------------------------------------------------------
// GEMM1 + exp + per-(b,j) row-mean:
//   K[b, j*64+m] = exp(-2*(h2[b]+d2[jm]-2*h.dom_jm)) ; sj[b,j] = mean_m K
// block: 64 b-rows x 64 m-cols (one j per block), 256 threads, 4x4 microtile
// ---------------------------------------------------------------------------
__global__ __launch_bounds__(256) void gemm1_kernel(const float* __restrict__ h,
                                                    const float* __restrict__ dom,
                                                    const float* __restrict__ h2,
                                                    const float* __restrict__ d2,
                                                    float* __restrict__ Kmat,
                                                    float* __restrict__ sj) {
    const int b0 = blockIdx.x * 64;
    const int j = blockIdx.y;
    const int p0 = j * 64;

    __shared__ float As[32][68];
    __shared__ float Bs[32][68];
    __shared__ float rowsum[64];

    int tid = threadIdx.x;
    int tx = tid & 15, ty = tid >> 4;

    float c[4][4] = {};

    for (int kk = 0; kk < F_SZ; kk += 32) {
        for (int l = 0; l < 2; ++l) {
            int idx = tid + l * 256;        // 0..511
            int r = idx >> 3;               // row 0..63
            int c4 = (idx & 7) << 2;        // col 0,4,..,28
            float4 va = *(const float4*)&h[(size_t)(b0 + r) * F_SZ + kk + c4];
            As[c4 + 0][r] = va.x; As[c4 + 1][r] = va.y;
            As[c4 + 2][r] = va.z; As[c4 + 3][r] = va.w;
            float4 vb = *(const float4*)&dom[(size_t)(p0 + r) * F_SZ + kk + c4];
            Bs[c4 + 0][r] = vb.x; Bs[c4 + 1][r] = vb.y;
            Bs[c4 + 2][r] = vb.z; Bs[c4 + 3][r] = vb.w;
        }
        __syncthreads();
        for (int k = 0; k < 32; ++k) {
            float a[4], bv[4];
            for (int i = 0; i < 4; ++i) a[i] = As[k][ty * 4 + i];
            for (int i = 0; i < 4; ++i) bv[i] = Bs[k][tx * 4 + i];
            for (int i = 0; i < 4; ++i)
                for (int l2 = 0; l2 < 4; ++l2) c[i][l2] += a[i] * bv[l2];
        }
        __syncthreads();
    }

    if (tid < 64) rowsum[tid] = 0.f;
    __syncthreads();

    float myrows[4] = {};
    for (int i = 0; i < 4; ++i) {
        int b = b0 + ty * 4 + i;
        float h2v = h2[b];
        for (int l = 0; l < 4; ++l) {
            int p = p0 + tx * 4 + l;
            float sq = h2v + d2[p] - 2.f * c[i][l];
            float kv = __expf(GAUSS_COEF * sq);
            Kmat[(size_t)b * P_SZ + p] = kv;
            myrows[i] += kv;
        }
    }
    for (int i = 0; i < 4; ++i) atomicAdd(&rowsum[ty * 4 + i], myrows[i]);
    __syncthreads();
    if (tid < 64) sj[(size_t)(b0 + tid) * J_SZ + j] = rowsum[tid] * (1.f / M_SZ);
}

// ---------------------------------------------------------------------------
// softmax over J of logit = 2*sj - kdd - 1   (= -mmd, softness=1)
// ---------------------------------------------------------------------------
__global__ __launch_bounds__(256) void softmax_kernel(const float* __restrict__ sj,
                                                      const float* __restrict__ kdd,
                                                      float* __restrict__ prob) {
    __shared__ float skdd[J_SZ];
    if (threadIdx.x < J_SZ) skdd[threadIdx.x] = kdd[threadIdx.x];
    __syncthreads();
    int b = blockIdx.x * blockDim.x + threadIdx.x;
    float logit[J_SZ];
    float mx = -1e30f;
    for (int j = 0; j < J_SZ; ++j) {
        float v = 2.f * sj[(size_t)b * J_SZ + j] - skdd[j] - 1.f;
        logit[j] = v;
        mx = fmaxf(mx, v);
    }
    float s = 0.f;
    for (int j = 0; j < J_SZ; ++j) {
        logit[j] = __expf(logit[j] - mx);
        s += logit[j];
    }
    float inv = 1.f / s;
    for (int j = 0; j < J_SZ; ++j) prob[(size_t)b * J_SZ + j] = logit[j] * inv;
}

// ---------------------------------------------------------------------------
// GEMM2: out[b,u] = sum_p (prob[b,p>>6]*K[b,p]) * W[p,u] + sum_j prob[b,j]*bias[j,u]
// block: 64 b-rows x 64 u-cols, 256 threads, 4x4 microtile
// ---------------------------------------------------------------------------
__global__ __launch_bounds__(256) void gemm2_kernel(const float* __restrict__ Kmat,
                                                    const float* __restrict__ prob,
                                                    const float* __restrict__ W,
                                                    const float* __restrict__ bias,
                                                    float* __restrict__ out) {
    const int b0 = blockIdx.x * 64;
    const int u0 = blockIdx.y * 64;

    __shared__ float As[32][68];
    __shared__ float Bs[32][68];
    __shared__ float BiasS[J_SZ][64];

    int tid = threadIdx.x;
    int tx = tid & 15, ty = tid >> 4;

    // stage bias tile for the epilogue
    for (int l = 0; l < 4; ++l) {
        int idx = tid + l * 256;           // 0..1023 = 16 j x 64 u
        int jj = idx >> 6, uu = idx & 63;
        BiasS[jj][uu] = bias[(size_t)jj * U_SZ + u0 + uu];
    }

    float c[4][4] = {};

    for (int kk = 0; kk < P_SZ; kk += 32) {
        // A tile: 64 b-rows x 32 p-cols, scaled by prob[b, p>>6]
        for (int l = 0; l < 2; ++l) {
            int idx = tid + l * 256;
            int r = idx >> 3;              // b-row 0..63
            int c4 = (idx & 7) << 2;       // p-col 0,4,..,28
            int p = kk + c4;
            int jj = p >> 6;               // constant across the float4
            float pf = prob[(size_t)(b0 + r) * J_SZ + jj];
            float4 va = *(const float4*)&Kmat[(size_t)(b0 + r) * P_SZ + p];
            As[c4 + 0][r] = va.x * pf; As[c4 + 1][r] = va.y * pf;
            As[c4 + 2][r] = va.z * pf; As[c4 + 3][r] = va.w * pf;
        }
        // B tile: 32 p-rows x 64 u-cols (no transpose needed)
        for (int l = 0; l < 2; ++l) {
            int idx = tid + l * 256;
            int r = idx >> 4;              // p-row 0..31
            int c4 = (idx & 15) << 2;      // u-col 0,4,..,60
            float4 vb = *(const float4*)&W[(size_t)(kk + r) * U_SZ + u0 + c4];
            *(float4*)&Bs[r][c4] = vb;
        }
        __syncthreads();
        for (int k = 0; k < 32; ++k) {
            float a[4], bv[4];
            for (int i = 0; i < 4; ++i) a[i] = As[k][ty * 4 + i];
            for (int i = 0; i < 4; ++i) bv[i] = Bs[k][tx * 4 + i];
            for (int i = 0; i < 4; ++i)
                for (int l2 = 0; l2 < 4; ++l2) c[i][l2] += a[i] * bv[l2];
        }
        __syncthreads();
    }

    for (int i = 0; i < 4; ++i) {
        int b = b0 + ty * 4 + i;
        float pr[J_SZ];
        for (int j = 0; j < J_SZ; ++j) pr[j] = prob[(size_t)b * J_SZ + j];
        for (int l = 0; l < 4; ++l) {
            int u = u0 + tx * 4 + l;
            float acc = c[i][l];
            for (int j = 0; j < J_SZ; ++j) acc += pr[j] * BiasS[j][tx * 4 + l];
            out[(size_t)b * U_SZ + u] = acc;
        }
    }
}

// ---------------------------------------------------------------------------
extern "C" void kernel_launch(void* const* d_in, const int* in_sizes, int n_in,
                              void* d_out, int out_size, void* d_ws, size_t ws_size,
                              hipStream_t stream) {
    const float* h    = (const float*)d_in[0];   // [B,F]
    const float* dom  = (const float*)d_in[1];   // [J,M,F]
    const float* W    = (const float*)d_in[2];   // [J,M,U]
    const float* bias = (const float*)d_in[3];   // [J,U]
    float* out = (float*)d_out;                  // [B,U]

    float* ws   = (float*)d_ws;
    float* Kmat = ws;                                  // B*P
    float* h2   = Kmat + (size_t)B_SZ * P_SZ;          // B
    float* d2   = h2 + B_SZ;                           // P
    float* kdd  = d2 + P_SZ;                           // J
    float* sj   = kdd + J_SZ;                          // B*J
    float* prob = sj + (size_t)B_SZ * J_SZ;            // B*J

    h2_kernel<<<B_SZ, 64, 0, stream>>>(h, h2);
    dom_kernel<<<J_SZ, 256, 0, stream>>>(dom, d2, kdd);
    gemm1_kernel<<<dim3(B_SZ / 64, J_SZ), 256, 0, stream>>>(h, dom, h2, d2, Kmat, sj);
    softmax_kernel<<<B_SZ / 256, 256, 0, stream>>>(sj, kdd, prob);
    gemm2_kernel<<<dim3(B_SZ / 64, U_SZ / 64), 256, 0, stream>>>(Kmat, prob, W, bias, out);
}

// Round 2
// 227.975 us; speedup vs baseline: 2.1260x; 2.1260x over previous
//
#include <hip/hip_runtime.h>
#include <math.h>

#define B_SZ 4096
#define F_SZ 512
#define J_SZ 16
#define M_SZ 64
#define U_SZ 512
#define P_SZ (J_SZ * M_SZ)   // 1024

// K(x,y) = exp(-||x-y||^2 / (2*sigma^2)), sigma=0.5 -> exp(-2*sqdist)
#define GAUSS_COEF (-2.0f)

// ---------------------------------------------------------------------------
// h2[b] = sum_f h[b,f]^2   (one wave per row)
// ---------------------------------------------------------------------------
__global__ __launch_bounds__(64) void h2_kernel(const float* __restrict__ h,
                                                float* __restrict__ h2) {
    int b = blockIdx.x;
    int lane = threadIdx.x;
    const float4* row = (const float4*)(h + (size_t)b * F_SZ);
    float s = 0.f;
    for (int i = lane; i < F_SZ / 4; i += 64) {
        float4 v = row[i];
        s += v.x * v.x + v.y * v.y + v.z * v.z + v.w * v.w;
    }
    for (int off = 32; off; off >>= 1) s += __shfl_down(s, off);
    if (lane == 0) h2[b] = s;
}

// ---------------------------------------------------------------------------
// Per-j Gram matrix G = D_j . D_j^T  (64x64, K=512) via LDS tiling.
//   d2[j,m]  = G[m,m]
//   kdd[j]   = mean_{m,n} exp(-2*(d2m + d2n - 2*G[m,n]))
// one block (256 thr, 4x4 microtile) per j — same microkernel as gemm1.
// ---------------------------------------------------------------------------
__global__ __launch_bounds__(256) void dom_kernel(const float* __restrict__ dom,
                                                  float* __restrict__ d2,
                                                  float* __restrict__ kdd) {
    int j = blockIdx.x;
    const float* base = dom + (size_t)j * M_SZ * F_SZ;

    __shared__ float As[32][68];
    __shared__ float diag[M_SZ];
    __shared__ float red[256];

    int tid = threadIdx.x;
    int tx = tid & 15, ty = tid >> 4;

    float c[4][4] = {};

    for (int kk = 0; kk < F_SZ; kk += 32) {
        // stage 64 rows x 32 k-cols, transposed (As[k][row]) — load once,
        // used as both A and B (Gram is symmetric).
        for (int l = 0; l < 2; ++l) {
            int idx = tid + l * 256;        // 0..511
            int r = idx >> 3;               // row 0..63
            int c4 = (idx & 7) << 2;        // col 0,4,..,28
            float4 v = *(const float4*)&base[(size_t)r * F_SZ + kk + c4];
            As[c4 + 0][r] = v.x; As[c4 + 1][r] = v.y;
            As[c4 + 2][r] = v.z; As[c4 + 3][r] = v.w;
        }
        __syncthreads();
        for (int k = 0; k < 32; ++k) {
            float a[4], bv[4];
            for (int i = 0; i < 4; ++i) a[i] = As[k][ty * 4 + i];
            for (int i = 0; i < 4; ++i) bv[i] = As[k][tx * 4 + i];
            for (int i = 0; i < 4; ++i)
                for (int l2 = 0; l2 < 4; ++l2) c[i][l2] += a[i] * bv[l2];
        }
        __syncthreads();
    }

    // diagonal -> d2
    if (tx == ty) {
        for (int i = 0; i < 4; ++i) diag[ty * 4 + i] = c[i][i];
    }
    __syncthreads();
    if (tid < M_SZ) d2[j * M_SZ + tid] = diag[tid];

    // kdd = mean exp(-2*(d2m + d2n - 2*G))
    float acc = 0.f;
    for (int i = 0; i < 4; ++i) {
        float dm = diag[ty * 4 + i];
        for (int l = 0; l < 4; ++l) {
            float sq = dm + diag[tx * 4 + l] - 2.f * c[i][l];
            acc += __expf(GAUSS_COEF * sq);
        }
    }
    red[tid] = acc;
    __syncthreads();
    for (int off = 128; off; off >>= 1) {
        if (tid < off) red[tid] += red[tid + off];
        __syncthreads();
    }
    if (tid == 0) kdd[j] = red[0] * (1.f / (M_SZ * M_SZ));
}

// ---------------------------------------------------------------------------
// GEMM1 + exp + per-(b,j) row-mean:
//   K[b, j*64+m] = exp(-2*(h2[b]+d2[jm]-2*h.dom_jm)) ; sj[b,j] = mean_m K
// block: 64 b-rows x 64 m-cols (one j per block), 256 threads, 4x4 microtile
// ---------------------------------------------------------------------------
__global__ __launch_bounds__(256) void gemm1_kernel(const float* __restrict__ h,
                                                    const float* __restrict__ dom,
                                                    const float* __restrict__ h2,
                                                    const float* __restrict__ d2,
                                                    float* __restrict__ Kmat,
                                                    float* __restrict__ sj) {
    const int b0 = blockIdx.x * 64;
    const int j = blockIdx.y;
    const int p0 = j * 64;

    __shared__ float As[32][68];
    __shared__ float Bs[32][68];
    __shared__ float rowsum[64];

    int tid = threadIdx.x;
    int tx = tid & 15, ty = tid >> 4;

    float c[4][4] = {};

    for (int kk = 0; kk < F_SZ; kk += 32) {
        for (int l = 0; l < 2; ++l) {
            int idx = tid + l * 256;        // 0..511
            int r = idx >> 3;               // row 0..63
            int c4 = (idx & 7) << 2;        // col 0,4,..,28
            float4 va = *(const float4*)&h[(size_t)(b0 + r) * F_SZ + kk + c4];
            As[c4 + 0][r] = va.x; As[c4 + 1][r] = va.y;
            As[c4 + 2][r] = va.z; As[c4 + 3][r] = va.w;
            float4 vb = *(const float4*)&dom[(size_t)(p0 + r) * F_SZ + kk + c4];
            Bs[c4 + 0][r] = vb.x; Bs[c4 + 1][r] = vb.y;
            Bs[c4 + 2][r] = vb.z; Bs[c4 + 3][r] = vb.w;
        }
        __syncthreads();
        for (int k = 0; k < 32; ++k) {
            float a[4], bv[4];
            for (int i = 0; i < 4; ++i) a[i] = As[k][ty * 4 + i];
            for (int i = 0; i < 4; ++i) bv[i] = Bs[k][tx * 4 + i];
            for (int i = 0; i < 4; ++i)
                for (int l2 = 0; l2 < 4; ++l2) c[i][l2] += a[i] * bv[l2];
        }
        __syncthreads();
    }

    if (tid < 64) rowsum[tid] = 0.f;
    __syncthreads();

    float myrows[4] = {};
    for (int i = 0; i < 4; ++i) {
        int b = b0 + ty * 4 + i;
        float h2v = h2[b];
        for (int l = 0; l < 4; ++l) {
            int p = p0 + tx * 4 + l;
            float sq = h2v + d2[p] - 2.f * c[i][l];
            float kv = __expf(GAUSS_COEF * sq);
            Kmat[(size_t)b * P_SZ + p] = kv;
            myrows[i] += kv;
        }
    }
    for (int i = 0; i < 4; ++i) atomicAdd(&rowsum[ty * 4 + i], myrows[i]);
    __syncthreads();
    if (tid < 64) sj[(size_t)(b0 + tid) * J_SZ + j] = rowsum[tid] * (1.f / M_SZ);
}

// ---------------------------------------------------------------------------
// softmax over J of logit = 2*sj - kdd - 1   (= -mmd, softness=1)
// ---------------------------------------------------------------------------
__global__ __launch_bounds__(256) void softmax_kernel(const float* __restrict__ sj,
                                                      const float* __restrict__ kdd,
                                                      float* __restrict__ prob) {
    __shared__ float skdd[J_SZ];
    if (threadIdx.x < J_SZ) skdd[threadIdx.x] = kdd[threadIdx.x];
    __syncthreads();
    int b = blockIdx.x * blockDim.x + threadIdx.x;
    float logit[J_SZ];
    float mx = -1e30f;
    for (int j = 0; j < J_SZ; ++j) {
        float v = 2.f * sj[(size_t)b * J_SZ + j] - skdd[j] - 1.f;
        logit[j] = v;
        mx = fmaxf(mx, v);
    }
    float s = 0.f;
    for (int j = 0; j < J_SZ; ++j) {
        logit[j] = __expf(logit[j] - mx);
        s += logit[j];
    }
    float inv = 1.f / s;
    for (int j = 0; j < J_SZ; ++j) prob[(size_t)b * J_SZ + j] = logit[j] * inv;
}

// ---------------------------------------------------------------------------
// GEMM2: out[b,u] = sum_p (prob[b,p>>6]*K[b,p]) * W[p,u] + sum_j prob[b,j]*bias[j,u]
// block: 64 b-rows x 64 u-cols, 256 threads, 4x4 microtile
// ---------------------------------------------------------------------------
__global__ __launch_bounds__(256) void gemm2_kernel(const float* __restrict__ Kmat,
                                                    const float* __restrict__ prob,
                                                    const float* __restrict__ W,
                                                    const float* __restrict__ bias,
                                                    float* __restrict__ out) {
    const int b0 = blockIdx.x * 64;
    const int u0 = blockIdx.y * 64;

    __shared__ float As[32][68];
    __shared__ float Bs[32][68];
    __shared__ float BiasS[J_SZ][64];

    int tid = threadIdx.x;
    int tx = tid & 15, ty = tid >> 4;

    // stage bias tile for the epilogue
    for (int l = 0; l < 4; ++l) {
        int idx = tid + l * 256;           // 0..1023 = 16 j x 64 u
        int jj = idx >> 6, uu = idx & 63;
        BiasS[jj][uu] = bias[(size_t)jj * U_SZ + u0 + uu];
    }

    float c[4][4] = {};

    for (int kk = 0; kk < P_SZ; kk += 32) {
        // A tile: 64 b-rows x 32 p-cols, scaled by prob[b, p>>6]
        for (int l = 0; l < 2; ++l) {
            int idx = tid + l * 256;
            int r = idx >> 3;              // b-row 0..63
            int c4 = (idx & 7) << 2;       // p-col 0,4,..,28
            int p = kk + c4;
            int jj = p >> 6;               // constant across the float4
            float pf = prob[(size_t)(b0 + r) * J_SZ + jj];
            float4 va = *(const float4*)&Kmat[(size_t)(b0 + r) * P_SZ + p];
            As[c4 + 0][r] = va.x * pf; As[c4 + 1][r] = va.y * pf;
            As[c4 + 2][r] = va.z * pf; As[c4 + 3][r] = va.w * pf;
        }
        // B tile: 32 p-rows x 64 u-cols (no transpose needed)
        for (int l = 0; l < 2; ++l) {
            int idx = tid + l * 256;
            int r = idx >> 4;              // p-row 0..31
            int c4 = (idx & 15) << 2;      // u-col 0,4,..,60
            float4 vb = *(const float4*)&W[(size_t)(kk + r) * U_SZ + u0 + c4];
            *(float4*)&Bs[r][c4] = vb;
        }
        __syncthreads();
        for (int k = 0; k < 32; ++k) {
            float a[4], bv[4];
            for (int i = 0; i < 4; ++i) a[i] = As[k][ty * 4 + i];
            for (int i = 0; i < 4; ++i) bv[i] = Bs[k][tx * 4 + i];
            for (int i = 0; i < 4; ++i)
                for (int l2 = 0; l2 < 4; ++l2) c[i][l2] += a[i] * bv[l2];
        }
        __syncthreads();
    }

    for (int i = 0; i < 4; ++i) {
        int b = b0 + ty * 4 + i;
        float pr[J_SZ];
        for (int j = 0; j < J_SZ; ++j) pr[j] = prob[(size_t)b * J_SZ + j];
        for (int l = 0; l < 4; ++l) {
            int u = u0 + tx * 4 + l;
            float acc = c[i][l];
            for (int j = 0; j < J_SZ; ++j) acc += pr[j] * BiasS[j][tx * 4 + l];
            out[(size_t)b * U_SZ + u] = acc;
        }
    }
}

// ---------------------------------------------------------------------------
extern "C" void kernel_launch(void* const* d_in, const int* in_sizes, int n_in,
                              void* d_out, int out_size, void* d_ws, size_t ws_size,
                              hipStream_t stream) {
    const float* h    = (const float*)d_in[0];   // [B,F]
    const float* dom  = (const float*)d_in[1];   // [J,M,F]
    const float* W    = (const float*)d_in[2];   // [J,M,U]
    const float* bias = (const float*)d_in[3];   // [J,U]
    float* out = (float*)d_out;                  // [B,U]

    float* ws   = (float*)d_ws;
    float* Kmat = ws;                                  // B*P
    float* h2   = Kmat + (size_t)B_SZ * P_SZ;          // B
    float* d2   = h2 + B_SZ;                           // P
    float* kdd  = d2 + P_SZ;                           // J
    float* sj   = kdd + J_SZ;                          // B*J
    float* prob = sj + (size_t)B_SZ * J_SZ;            // B*J

    h2_kernel<<<B_SZ, 64, 0, stream>>>(h, h2);
    dom_kernel<<<J_SZ, 256, 0, stream>>>(dom, d2, kdd);
    gemm1_kernel<<<dim3(B_SZ / 64, J_SZ), 256, 0, stream>>>(h, dom, h2, d2, Kmat, sj);
    softmax_kernel<<<B_SZ / 256, 256, 0, stream>>>(sj, kdd, prob);
    gemm2_kernel<<<dim3(B_SZ / 64, U_SZ / 64), 256, 0, stream>>>(Kmat, prob, W, bias, out);
}

// Round 3
// 129.226 us; speedup vs baseline: 3.7506x; 1.7641x over previous
//
#include <hip/hip_runtime.h>
#include <math.h>

typedef unsigned short ushort_t;
typedef __attribute__((ext_vector_type(8))) short bf16x8;
typedef __attribute__((ext_vector_type(4))) float f32x4;

#define B_SZ 4096
#define F_SZ 512
#define J_SZ 16
#define M_SZ 64
#define U_SZ 512
#define P_SZ 1024

__device__ __forceinline__ ushort_t f2bf(float f) {
    union { float f; unsigned int u; } v; v.f = f;
    unsigned int r = (v.u + 0x7FFFu + ((v.u >> 16) & 1u)) >> 16;
    return (ushort_t)r;
}
__device__ __forceinline__ float bf2f(ushort_t u) {
    union { unsigned int u; float f; } v; v.u = ((unsigned int)u) << 16;
    return v.f;
}

// async global->LDS, 16 bytes per lane (wave-uniform base + lane*16)
__device__ __forceinline__ void gload_lds16(const void* g, void* l) {
    __builtin_amdgcn_global_load_lds(
        (const __attribute__((address_space(1))) unsigned int*)g,
        (__attribute__((address_space(3))) unsigned int*)l, 16, 0, 0);
}

// ---------------------------------------------------------------------------
// cvt_h: h fp32 -> bf16, h2[b] = ||h_b||^2.  4 rows per block (1 wave each).
// ---------------------------------------------------------------------------
__global__ __launch_bounds__(256) void cvt_h(const float* __restrict__ h,
                                             ushort_t* __restrict__ hbf,
                                             float* __restrict__ h2) {
    int b = blockIdx.x * 4 + (threadIdx.x >> 6);
    int lane = threadIdx.x & 63;
    const float4* row = (const float4*)(h + (size_t)b * F_SZ);
    ushort4* orow = (ushort4*)(hbf + (size_t)b * F_SZ);
    float s = 0.f;
    for (int i = lane; i < F_SZ / 4; i += 64) {
        float4 v = row[i];
        s += v.x * v.x + v.y * v.y + v.z * v.z + v.w * v.w;
        ushort4 o; o.x = f2bf(v.x); o.y = f2bf(v.y); o.z = f2bf(v.z); o.w = f2bf(v.w);
        orow[i] = o;
    }
    for (int off = 32; off; off >>= 1) s += __shfl_down(s, off);
    if (lane == 0) h2[b] = s;
}

// ---------------------------------------------------------------------------
// cvt_dom: dom fp32 -> bf16, d2[p] = ||dom_p||^2, zero Gmat. 4 rows/block.
// ---------------------------------------------------------------------------
__global__ __launch_bounds__(256) void cvt_dom(const float* __restrict__ dom,
                                               ushort_t* __restrict__ dombf,
                                               float* __restrict__ d2,
                                               float* __restrict__ Gmat) {
    Gmat[blockIdx.x * 256 + threadIdx.x] = 0.f;   // 256 blk * 256 thr = 65536
    int p = blockIdx.x * 4 + (threadIdx.x >> 6);
    int lane = threadIdx.x & 63;
    const float4* row = (const float4*)(dom + (size_t)p * F_SZ);
    ushort4* orow = (ushort4*)(dombf + (size_t)p * F_SZ);
    float s = 0.f;
    for (int i = lane; i < F_SZ / 4; i += 64) {
        float4 v = row[i];
        s += v.x * v.x + v.y * v.y + v.z * v.z + v.w * v.w;
        ushort4 o; o.x = f2bf(v.x); o.y = f2bf(v.y); o.z = f2bf(v.z); o.w = f2bf(v.w);
        orow[i] = o;
    }
    for (int off = 32; off; off >>= 1) s += __shfl_down(s, off);
    if (lane == 0) d2[p] = s;
}

// ---------------------------------------------------------------------------
// gram_kernel: partial Gram G[j] += D_j(:,kc) . D_j(:,kc)^T  (fp32, LDS tile)
// grid (16 j, 4 kc), 256 thr, 4x4 microtile over 64x64.
// ---------------------------------------------------------------------------
__global__ __launch_bounds__(256) void gram_kernel(const float* __restrict__ dom,
                                                   float* __restrict__ Gmat) {
    int j = blockIdx.x;
    const float* base = dom + (size_t)j * M_SZ * F_SZ + blockIdx.y * 128;
    __shared__ float As[32][68];
    int tid = threadIdx.x;
    int tx = tid & 15, ty = tid >> 4;
    float c[4][4] = {};
    for (int kk = 0; kk < 128; kk += 32) {
        for (int l = 0; l < 2; ++l) {
            int idx = tid + l * 256;
            int r = idx >> 3, c4 = (idx & 7) << 2;
            float4 v = *(const float4*)&base[(size_t)r * F_SZ + kk + c4];
            As[c4 + 0][r] = v.x; As[c4 + 1][r] = v.y;
            As[c4 + 2][r] = v.z; As[c4 + 3][r] = v.w;
        }
        __syncthreads();
        for (int k = 0; k < 32; ++k) {
            float a[4], bv[4];
            for (int i = 0; i < 4; ++i) a[i] = As[k][ty * 4 + i];
            for (int i = 0; i < 4; ++i) bv[i] = As[k][tx * 4 + i];
            for (int i = 0; i < 4; ++i)
                for (int l2 = 0; l2 < 4; ++l2) c[i][l2] += a[i] * bv[l2];
        }
        __syncthreads();
    }
    for (int i = 0; i < 4; ++i)
        for (int l2 = 0; l2 < 4; ++l2)
            atomicAdd(&Gmat[(size_t)j * 4096 + (ty * 4 + i) * 64 + tx * 4 + l2], c[i][l2]);
}

// ---------------------------------------------------------------------------
// kdd_reduce: kdd[j] = mean_{m,n} exp(-2*(d2m + d2n - 2*G[m,n]))
// ---------------------------------------------------------------------------
__global__ __launch_bounds__(256) void kdd_reduce(const float* __restrict__ Gmat,
                                                  const float* __restrict__ d2,
                                                  float* __restrict__ kdd) {
    int j = blockIdx.x, tid = threadIdx.x;
    __shared__ float sd2[M_SZ];
    __shared__ float red[256];
    if (tid < M_SZ) sd2[tid] = d2[j * M_SZ + tid];
    __syncthreads();
    float acc = 0.f;
    for (int s = tid; s < 4096; s += 256) {
        int m = s >> 6, n = s & 63;
        float sq = sd2[m] + sd2[n] - 2.f * Gmat[(size_t)j * 4096 + s];
        acc += __expf(-2.f * sq);
    }
    red[tid] = acc;
    __syncthreads();
    for (int off = 128; off; off >>= 1) {
        if (tid < off) red[tid] += red[tid + off];
        __syncthreads();
    }
    if (tid == 0) kdd[j] = red[0] * (1.f / 4096.f);
}

// ---------------------------------------------------------------------------
// gemm1_mfma: cross = hbf . dombf^T  (both [rows][512] bf16, K-contiguous)
// 128x128 tile, BK=32, 4 waves (2x2), 4x4 16x16x32 frags per wave.
// Epilogue: K = exp(-2*(h2+d2-2c)) -> Kbf (bf16), sj row-sums (no atomics).
// ---------------------------------------------------------------------------
__global__ __launch_bounds__(256) void gemm1_mfma(const ushort_t* __restrict__ hbf,
                                                  const ushort_t* __restrict__ dombf,
                                                  const float* __restrict__ h2,
                                                  const float* __restrict__ d2,
                                                  ushort_t* __restrict__ Kbf,
                                                  float* __restrict__ sj) {
    __shared__ short As[128 * 32];
    __shared__ short Bs[128 * 32];
    const int b0 = blockIdx.x * 128;
    const int p0 = blockIdx.y * 128;
    const int tid = threadIdx.x;
    const int wid = tid >> 6, lane = tid & 63;
    const int wm = wid >> 1, wn = wid & 1;
    const int lcol = lane & 15, quad = lane >> 4;

    f32x4 acc[4][4];
    for (int i = 0; i < 4; ++i)
        for (int n = 0; n < 4; ++n) acc[i][n] = (f32x4){0.f, 0.f, 0.f, 0.f};

    for (int kk = 0; kk < F_SZ; kk += 32) {
#pragma unroll
        for (int l = 0; l < 2; ++l) {
            int s = l * 256 + tid;          // 0..511
            int row = s >> 2, seg = s & 3;
            gload_lds16(hbf + (size_t)(b0 + row) * F_SZ + kk + seg * 8, &As[s * 8]);
            gload_lds16(dombf + (size_t)(p0 + row) * F_SZ + kk + seg * 8, &Bs[s * 8]);
        }
        __syncthreads();
        bf16x8 ar[4], br[4];
#pragma unroll
        for (int i = 0; i < 4; ++i) {
            ar[i] = *(const bf16x8*)&As[(wm * 64 + i * 16 + lcol) * 32 + quad * 8];
            br[i] = *(const bf16x8*)&Bs[(wn * 64 + i * 16 + lcol) * 32 + quad * 8];
        }
#pragma unroll
        for (int i = 0; i < 4; ++i)
#pragma unroll
            for (int n = 0; n < 4; ++n)
                acc[i][n] = __builtin_amdgcn_mfma_f32_16x16x32_bf16(ar[i], br[n], acc[i][n], 0, 0, 0);
        __syncthreads();
    }

    // epilogue
    const int jg = (p0 >> 6) + wn;          // this wave's j (64 cols per j)
    float d2v[4];
#pragma unroll
    for (int n = 0; n < 4; ++n) d2v[n] = d2[p0 + wn * 64 + n * 16 + lcol];

#pragma unroll
    for (int i = 0; i < 4; ++i) {
#pragma unroll
        for (int r = 0; r < 4; ++r) {
            int b = b0 + wm * 64 + i * 16 + quad * 4 + r;
            float h2v = h2[b];
            float rs = 0.f;
#pragma unroll
            for (int n = 0; n < 4; ++n) {
                int p = p0 + wn * 64 + n * 16 + lcol;
                float sq = h2v + d2v[n] - 2.f * acc[i][n][r];
                float kv = __expf(-2.f * sq);
                Kbf[(size_t)b * P_SZ + p] = f2bf(kv);
                rs += kv;
            }
            rs += __shfl_xor(rs, 1);
            rs += __shfl_xor(rs, 2);
            rs += __shfl_xor(rs, 4);
            rs += __shfl_xor(rs, 8);
            if (lcol == 0) sj[(size_t)b * J_SZ + jg] = rs * (1.f / M_SZ);
        }
    }
}

// ---------------------------------------------------------------------------
// softmax_scale: per b — prob = softmax(2*sj - kdd - 1), Kbf *= prob (in place)
// ---------------------------------------------------------------------------
__global__ __launch_bounds__(256) void softmax_scale(const float* __restrict__ sj,
                                                     const float* __restrict__ kdd,
                                                     ushort_t* __restrict__ Kbf,
                                                     float* __restrict__ prob) {
    int b = blockIdx.x, tid = threadIdx.x;
    __shared__ float pS[J_SZ];
    if (tid == 0) {
        float lg[J_SZ], mx = -1e30f;
        for (int j = 0; j < J_SZ; ++j) {
            lg[j] = 2.f * sj[(size_t)b * J_SZ + j] - kdd[j] - 1.f;
            mx = fmaxf(mx, lg[j]);
        }
        float s = 0.f;
        for (int j = 0; j < J_SZ; ++j) { lg[j] = __expf(lg[j] - mx); s += lg[j]; }
        float inv = 1.f / s;
        for (int j = 0; j < J_SZ; ++j) {
            pS[j] = lg[j] * inv;
            prob[(size_t)b * J_SZ + j] = pS[j];
        }
    }
    __syncthreads();
    ushort4* KR = (ushort4*)(Kbf + (size_t)b * P_SZ);
    float pf = pS[tid >> 4];                 // p = tid*4 -> j = tid>>4
    ushort4 v = KR[tid];
    v.x = f2bf(bf2f(v.x) * pf);
    v.y = f2bf(bf2f(v.y) * pf);
    v.z = f2bf(bf2f(v.z) * pf);
    v.w = f2bf(bf2f(v.w) * pf);
    KR[tid] = v;
}

// ---------------------------------------------------------------------------
// cvt_w: W [1024 p][512 u] fp32 -> Wt [512 u][1024 p] bf16 (LDS transpose)
// grid (16 p-tiles, 8 u-tiles)
// ---------------------------------------------------------------------------
__global__ __launch_bounds__(256) void cvt_w(const float* __restrict__ W,
                                             ushort_t* __restrict__ Wt) {
    int pt = blockIdx.x * 64, ut = blockIdx.y * 64;
    __shared__ ushort_t T[64][72];
    int tid = threadIdx.x;
#pragma unroll
    for (int l = 0; l < 4; ++l) {
        int s = l * 256 + tid;              // float4 index, 0..1023
        int r = s >> 4, c4 = (s & 15) << 2; // r = p-local, c4 = u-local
        float4 v = *(const float4*)&W[(size_t)(pt + r) * U_SZ + ut + c4];
        T[c4 + 0][r] = f2bf(v.x); T[c4 + 1][r] = f2bf(v.y);
        T[c4 + 2][r] = f2bf(v.z); T[c4 + 3][r] = f2bf(v.w);
    }
    __syncthreads();
#pragma unroll
    for (int l = 0; l < 4; ++l) {
        int s = l * 256 + tid;              // ushort4 index
        int r2 = s >> 4, c4 = (s & 15) << 2;
        ushort4 o; o.x = T[r2][c4 + 0]; o.y = T[r2][c4 + 1];
        o.z = T[r2][c4 + 2]; o.w = T[r2][c4 + 3];
        *(ushort4*)&Wt[(size_t)(ut + r2) * P_SZ + pt + c4] = o;
    }
}

// ---------------------------------------------------------------------------
// gemm2_mfma: out = Ks . Wt^T (+ sum_j prob*bias).  A [4096][1024] bf16,
// B = Wt [512][1024] bf16 (both K-contiguous). 128x64 tile, BK=32.
// ---------------------------------------------------------------------------
__global__ __launch_bounds__(256) void gemm2_mfma(const ushort_t* __restrict__ Ks,
                                                  const ushort_t* __restrict__ Wt,
                                                  const float* __restrict__ prob,
                                                  const float* __restrict__ bias,
                                                  float* __restrict__ out) {
    __shared__ short As[128 * 32];     // 8 KB
    __shared__ short Bs[64 * 32];      // 4 KB
    __shared__ float probS[128 * 16];  // 8 KB
    __shared__ float biasS[16 * 64];   // 4 KB
    const int b0 = blockIdx.x * 128;
    const int u0 = blockIdx.y * 64;
    const int tid = threadIdx.x;
    const int wid = tid >> 6, lane = tid & 63;
    const int wm = wid >> 1, wn = wid & 1;
    const int lcol = lane & 15, quad = lane >> 4;

    // stage prob rows + bias tile
#pragma unroll
    for (int l = 0; l < 2; ++l) {
        int s = l * 256 + tid;
        ((float4*)probS)[s] = ((const float4*)(prob + (size_t)b0 * J_SZ))[s];
    }
    {
        int rowj = tid >> 4, c4 = (tid & 15) << 2;
        *(float4*)&biasS[rowj * 64 + c4] = *(const float4*)&bias[(size_t)rowj * U_SZ + u0 + c4];
    }

    f32x4 acc[4][2];
    for (int i = 0; i < 4; ++i)
        for (int n = 0; n < 2; ++n) acc[i][n] = (f32x4){0.f, 0.f, 0.f, 0.f};

    for (int kk = 0; kk < P_SZ; kk += 32) {
#pragma unroll
        for (int l = 0; l < 2; ++l) {
            int s = l * 256 + tid;
            int row = s >> 2, seg = s & 3;
            gload_lds16(Ks + (size_t)(b0 + row) * P_SZ + kk + seg * 8, &As[s * 8]);
        }
        {
            int row = tid >> 2, seg = tid & 3;
            gload_lds16(Wt + (size_t)(u0 + row) * P_SZ + kk + seg * 8, &Bs[tid * 8]);
        }
        __syncthreads();
        bf16x8 ar[4], br[2];
#pragma unroll
        for (int i = 0; i < 4; ++i)
            ar[i] = *(const bf16x8*)&As[(wm * 64 + i * 16 + lcol) * 32 + quad * 8];
#pragma unroll
        for (int n = 0; n < 2; ++n)
            br[n] = *(const bf16x8*)&Bs[(wn * 32 + n * 16 + lcol) * 32 + quad * 8];
#pragma unroll
        for (int i = 0; i < 4; ++i)
#pragma unroll
            for (int n = 0; n < 2; ++n)
                acc[i][n] = __builtin_amdgcn_mfma_f32_16x16x32_bf16(ar[i], br[n], acc[i][n], 0, 0, 0);
        __syncthreads();
    }

    // epilogue: out = acc + sum_j prob[b,j]*bias[j,u]
    float bv[2][J_SZ];
#pragma unroll
    for (int n = 0; n < 2; ++n) {
        int col = wn * 32 + n * 16 + lcol;
#pragma unroll
        for (int j = 0; j < J_SZ; ++j) bv[n][j] = biasS[j * 64 + col];
    }
#pragma unroll
    for (int i = 0; i < 4; ++i) {
#pragma unroll
        for (int r = 0; r < 4; ++r) {
            int rowl = wm * 64 + i * 16 + quad * 4 + r;
            int b = b0 + rowl;
            const float* pr = &probS[rowl * 16];
#pragma unroll
            for (int n = 0; n < 2; ++n) {
                int col = wn * 32 + n * 16 + lcol;
                float bb = 0.f;
#pragma unroll
                for (int j = 0; j < J_SZ; ++j) bb += pr[j] * bv[n][j];
                out[(size_t)b * U_SZ + u0 + col] = acc[i][n][r] + bb;
            }
        }
    }
}

// ---------------------------------------------------------------------------
extern "C" void kernel_launch(void* const* d_in, const int* in_sizes, int n_in,
                              void* d_out, int out_size, void* d_ws, size_t ws_size,
                              hipStream_t stream) {
    const float* h    = (const float*)d_in[0];   // [B,F]
    const float* dom  = (const float*)d_in[1];   // [J,M,F]
    const float* W    = (const float*)d_in[2];   // [J,M,U]
    const float* bias = (const float*)d_in[3];   // [J,U]
    float* out = (float*)d_out;                  // [B,U]

    char* ws = (char*)d_ws;
    ushort_t* hbf   = (ushort_t*)ws;                         ws += (size_t)B_SZ * F_SZ * 2;  // 4 MB
    ushort_t* dombf = (ushort_t*)ws;                         ws += (size_t)P_SZ * F_SZ * 2;  // 1 MB
    ushort_t* Wt    = (ushort_t*)ws;                         ws += (size_t)U_SZ * P_SZ * 2;  // 1 MB
    ushort_t* Kbf   = (ushort_t*)ws;                         ws += (size_t)B_SZ * P_SZ * 2;  // 8 MB
    float* h2   = (float*)ws;  ws += B_SZ * 4;
    float* d2   = (float*)ws;  ws += P_SZ * 4;
    float* kdd  = (float*)ws;  ws += 64;
    float* sj   = (float*)ws;  ws += (size_t)B_SZ * J_SZ * 4;
    float* prob = (float*)ws;  ws += (size_t)B_SZ * J_SZ * 4;
    float* Gmat = (float*)ws;  ws += (size_t)J_SZ * M_SZ * M_SZ * 4;

    cvt_h<<<B_SZ / 4, 256, 0, stream>>>(h, hbf, h2);
    cvt_dom<<<P_SZ / 4, 256, 0, stream>>>(dom, dombf, d2, Gmat);
    gram_kernel<<<dim3(J_SZ, 4), 256, 0, stream>>>(dom, Gmat);
    kdd_reduce<<<J_SZ, 256, 0, stream>>>(Gmat, d2, kdd);
    gemm1_mfma<<<dim3(B_SZ / 128, P_SZ / 128), 256, 0, stream>>>(hbf, dombf, h2, d2, Kbf, sj);
    softmax_scale<<<B_SZ, 256, 0, stream>>>(sj, kdd, Kbf, prob);
    cvt_w<<<dim3(P_SZ / 64, U_SZ / 64), 256, 0, stream>>>(W, Wt);
    gemm2_mfma<<<dim3(B_SZ / 128, U_SZ / 64), 256, 0, stream>>>(Kbf, Wt, prob, bias, out);
}

// Round 4
// 111.197 us; speedup vs baseline: 4.3587x; 1.1621x over previous
//
#include <hip/hip_runtime.h>
#include <math.h>

typedef unsigned short ushort_t;
typedef __attribute__((ext_vector_type(8))) short bf16x8;
typedef __attribute__((ext_vector_type(4))) float f32x4;

#define B_SZ 4096
#define F_SZ 512
#define J_SZ 16
#define M_SZ 64
#define U_SZ 512
#define P_SZ 1024

__device__ __forceinline__ ushort_t f2bf(float f) {
    union { float f; unsigned int u; } v; v.f = f;
    unsigned int r = (v.u + 0x7FFFu + ((v.u >> 16) & 1u)) >> 16;
    return (ushort_t)r;
}

// async global->LDS, 16 bytes per lane (wave-uniform base + lane*16)
__device__ __forceinline__ void gload_lds16(const void* g, void* l) {
    __builtin_amdgcn_global_load_lds(
        (const __attribute__((address_space(1))) unsigned int*)g,
        (__attribute__((address_space(3))) unsigned int*)l, 16, 0, 0);
}

// ---------------------------------------------------------------------------
// prep: block-role fused preprocessing.
//   blocks [0,1024): h fp32->bf16 + h2          (4 rows/block)
//   blocks [1024,1280): dom fp32->bf16 + d2     (4 rows/block)
//   blocks [1280,1344): Gram partials Gpart[kc][j][64][64] (fp32, no atomics)
//   blocks [1344,1472): W [p][u] -> Wt [u][p] bf16 (64x64 LDS transpose)
// ---------------------------------------------------------------------------
__global__ __launch_bounds__(256) void prep_kernel(const float* __restrict__ h,
                                                   const float* __restrict__ dom,
                                                   const float* __restrict__ W,
                                                   ushort_t* __restrict__ hbf,
                                                   ushort_t* __restrict__ dombf,
                                                   ushort_t* __restrict__ Wt,
                                                   float* __restrict__ h2,
                                                   float* __restrict__ d2,
                                                   float* __restrict__ Gpart) {
    const int bid = blockIdx.x;
    const int tid = threadIdx.x;

    if (bid < 1024) {                       // ---- cvt_h ----
        int b = bid * 4 + (tid >> 6);
        int lane = tid & 63;
        const float4* row = (const float4*)(h + (size_t)b * F_SZ);
        ushort4* orow = (ushort4*)(hbf + (size_t)b * F_SZ);
        float s = 0.f;
        for (int i = lane; i < F_SZ / 4; i += 64) {
            float4 v = row[i];
            s += v.x * v.x + v.y * v.y + v.z * v.z + v.w * v.w;
            ushort4 o; o.x = f2bf(v.x); o.y = f2bf(v.y); o.z = f2bf(v.z); o.w = f2bf(v.w);
            orow[i] = o;
        }
        for (int off = 32; off; off >>= 1) s += __shfl_down(s, off);
        if (lane == 0) h2[b] = s;
    } else if (bid < 1280) {                // ---- cvt_dom ----
        int p = (bid - 1024) * 4 + (tid >> 6);
        int lane = tid & 63;
        const float4* row = (const float4*)(dom + (size_t)p * F_SZ);
        ushort4* orow = (ushort4*)(dombf + (size_t)p * F_SZ);
        float s = 0.f;
        for (int i = lane; i < F_SZ / 4; i += 64) {
            float4 v = row[i];
            s += v.x * v.x + v.y * v.y + v.z * v.z + v.w * v.w;
            ushort4 o; o.x = f2bf(v.x); o.y = f2bf(v.y); o.z = f2bf(v.z); o.w = f2bf(v.w);
            orow[i] = o;
        }
        for (int off = 32; off; off >>= 1) s += __shfl_down(s, off);
        if (lane == 0) d2[p] = s;
    } else if (bid < 1344) {                // ---- Gram partial ----
        int idx = bid - 1280;
        int j = idx >> 2, kc = idx & 3;
        const float* base = dom + (size_t)j * M_SZ * F_SZ + kc * 128;
        __shared__ float As[32][68];
        int tx = tid & 15, ty = tid >> 4;
        float c[4][4] = {};
        for (int kk = 0; kk < 128; kk += 32) {
            for (int l = 0; l < 2; ++l) {
                int s = tid + l * 256;
                int r = s >> 3, c4 = (s & 7) << 2;
                float4 v = *(const float4*)&base[(size_t)r * F_SZ + kk + c4];
                As[c4 + 0][r] = v.x; As[c4 + 1][r] = v.y;
                As[c4 + 2][r] = v.z; As[c4 + 3][r] = v.w;
            }
            __syncthreads();
            for (int k = 0; k < 32; ++k) {
                float a[4], bv[4];
                for (int i = 0; i < 4; ++i) a[i] = As[k][ty * 4 + i];
                for (int i = 0; i < 4; ++i) bv[i] = As[k][tx * 4 + i];
                for (int i = 0; i < 4; ++i)
                    for (int l2 = 0; l2 < 4; ++l2) c[i][l2] += a[i] * bv[l2];
            }
            __syncthreads();
        }
        float* gout = Gpart + ((size_t)kc * 16 + j) * 4096;
        for (int i = 0; i < 4; ++i)
            for (int l2 = 0; l2 < 4; ++l2)
                gout[(ty * 4 + i) * 64 + tx * 4 + l2] = c[i][l2];
    } else {                                // ---- cvt_w (transpose) ----
        int idx = bid - 1344;
        int pt = (idx >> 3) * 64, ut = (idx & 7) * 64;
        __shared__ ushort_t T[64][72];
        for (int l = 0; l < 4; ++l) {
            int s = l * 256 + tid;
            int r = s >> 4, c4 = (s & 15) << 2;
            float4 v = *(const float4*)&W[(size_t)(pt + r) * U_SZ + ut + c4];
            T[c4 + 0][r] = f2bf(v.x); T[c4 + 1][r] = f2bf(v.y);
            T[c4 + 2][r] = f2bf(v.z); T[c4 + 3][r] = f2bf(v.w);
        }
        __syncthreads();
        for (int l = 0; l < 4; ++l) {
            int s = l * 256 + tid;
            int r2 = s >> 4, c4 = (s & 15) << 2;
            ushort4 o; o.x = T[r2][c4 + 0]; o.y = T[r2][c4 + 1];
            o.z = T[r2][c4 + 2]; o.w = T[r2][c4 + 3];
            *(ushort4*)&Wt[(size_t)(ut + r2) * P_SZ + pt + c4] = o;
        }
    }
}

// ---------------------------------------------------------------------------
// kdd_reduce: kdd[j] = mean_{m,n} exp(-2*(d2m + d2n - 2*sum_kc Gpart))
// ---------------------------------------------------------------------------
__global__ __launch_bounds__(256) void kdd_reduce(const float* __restrict__ Gpart,
                                                  const float* __restrict__ d2,
                                                  float* __restrict__ kdd) {
    int j = blockIdx.x, tid = threadIdx.x;
    __shared__ float sd2[M_SZ];
    __shared__ float red[256];
    if (tid < M_SZ) sd2[tid] = d2[j * M_SZ + tid];
    __syncthreads();
    const float* g0 = Gpart + (size_t)(0 * 16 + j) * 4096;
    const float* g1 = Gpart + (size_t)(1 * 16 + j) * 4096;
    const float* g2 = Gpart + (size_t)(2 * 16 + j) * 4096;
    const float* g3 = Gpart + (size_t)(3 * 16 + j) * 4096;
    float acc = 0.f;
    for (int s = tid; s < 4096; s += 256) {
        float G = g0[s] + g1[s] + g2[s] + g3[s];
        int m = s >> 6, n = s & 63;
        acc += __expf(-2.f * (sd2[m] + sd2[n] - 2.f * G));
    }
    red[tid] = acc;
    __syncthreads();
    for (int off = 128; off; off >>= 1) {
        if (tid < off) red[tid] += red[tid + off];
        __syncthreads();
    }
    if (tid == 0) kdd[j] = red[0] * (1.f / 4096.f);
}

// ---------------------------------------------------------------------------
// gemm1_mfma: cross = hbf . dombf^T, 64x128 tile (512 blocks, 2/CU), BK=32.
// Waves 2x2: wm in {0,1} -> 32 rows, wn in {0,1} -> 64 cols (= one j).
// Epilogue: K = exp(-2*(h2+d2-2c)) -> sj (shfl) ; Kbf via LDS repack store.
// ---------------------------------------------------------------------------
__global__ __launch_bounds__(256) void gemm1_mfma(const ushort_t* __restrict__ hbf,
                                                  const ushort_t* __restrict__ dombf,
                                                  const float* __restrict__ h2,
                                                  const float* __restrict__ d2,
                                                  ushort_t* __restrict__ Kbf,
                                                  float* __restrict__ sj) {
    __shared__ ushort_t smem[8448];          // 16.9 KB: As(2048) + Bs(4096) | LDSC 64x132
    short* As = (short*)smem;                // 64 x 32
    short* Bs = (short*)(smem + 2048);       // 128 x 32
    const int b0 = blockIdx.x * 64;
    const int p0 = blockIdx.y * 128;
    const int tid = threadIdx.x;
    const int wid = tid >> 6, lane = tid & 63;
    const int wm = wid >> 1, wn = wid & 1;
    const int lcol = lane & 15, quad = lane >> 4;

    f32x4 acc[2][4];
    for (int i = 0; i < 2; ++i)
        for (int n = 0; n < 4; ++n) acc[i][n] = (f32x4){0.f, 0.f, 0.f, 0.f};

    for (int kk = 0; kk < F_SZ; kk += 32) {
        {
            int row = tid >> 2, seg = tid & 3;
            gload_lds16(hbf + (size_t)(b0 + row) * F_SZ + kk + seg * 8, &As[tid * 8]);
        }
#pragma unroll
        for (int l = 0; l < 2; ++l) {
            int s = l * 256 + tid;
            int row = s >> 2, seg = s & 3;
            gload_lds16(dombf + (size_t)(p0 + row) * F_SZ + kk + seg * 8, &Bs[s * 8]);
        }
        __syncthreads();
        bf16x8 ar[2], br[4];
#pragma unroll
        for (int i = 0; i < 2; ++i)
            ar[i] = *(const bf16x8*)&As[(wm * 32 + i * 16 + lcol) * 32 + quad * 8];
#pragma unroll
        for (int n = 0; n < 4; ++n)
            br[n] = *(const bf16x8*)&Bs[(wn * 64 + n * 16 + lcol) * 32 + quad * 8];
#pragma unroll
        for (int i = 0; i < 2; ++i)
#pragma unroll
            for (int n = 0; n < 4; ++n)
                acc[i][n] = __builtin_amdgcn_mfma_f32_16x16x32_bf16(ar[i], br[n], acc[i][n], 0, 0, 0);
        __syncthreads();
    }

    // ---- epilogue: exp, sj reduction, stash bf16 ----
    const int jg = (p0 >> 6) + wn;
    float d2v[4];
#pragma unroll
    for (int n = 0; n < 4; ++n) d2v[n] = d2[p0 + wn * 64 + n * 16 + lcol];

    unsigned int stash[2][4][2];
#pragma unroll
    for (int i = 0; i < 2; ++i) {
#pragma unroll
        for (int r = 0; r < 4; ++r) {
            int b = b0 + wm * 32 + i * 16 + quad * 4 + r;
            float h2v = h2[b];
            float rs = 0.f;
            ushort_t kv[4];
#pragma unroll
            for (int n = 0; n < 4; ++n) {
                float sq = h2v + d2v[n] - 2.f * acc[i][n][r];
                float kvf = __expf(-2.f * sq);
                kv[n] = f2bf(kvf);
                rs += kvf;
            }
            stash[i][r][0] = (unsigned int)kv[0] | ((unsigned int)kv[1] << 16);
            stash[i][r][1] = (unsigned int)kv[2] | ((unsigned int)kv[3] << 16);
            rs += __shfl_xor(rs, 1);
            rs += __shfl_xor(rs, 2);
            rs += __shfl_xor(rs, 4);
            rs += __shfl_xor(rs, 8);
            if (lcol == 0) sj[(size_t)b * J_SZ + jg] = rs * (1.f / M_SZ);
        }
    }

    // ---- repack: C-layout -> LDSC[64][132] -> coalesced 8B stores ----
    ushort_t* LDSC = smem;
#pragma unroll
    for (int i = 0; i < 2; ++i) {
#pragma unroll
        for (int r = 0; r < 4; ++r) {
            int row = wm * 32 + i * 16 + quad * 4 + r;
#pragma unroll
            for (int n = 0; n < 4; ++n) {
                ushort_t v = (ushort_t)(stash[i][r][n >> 1] >> ((n & 1) * 16));
                LDSC[row * 132 + wn * 64 + n * 16 + lcol] = v;
            }
        }
    }
    __syncthreads();
#pragma unroll
    for (int l = 0; l < 8; ++l) {
        int u = l * 256 + tid;               // 2048 ushort4 units
        int row = u >> 5, segc = (u & 31) * 4;
        ushort4 v = *(const ushort4*)&LDSC[row * 132 + segc];
        *(ushort4*)&Kbf[(size_t)(b0 + row) * P_SZ + p0 + segc] = v;
    }
}

// ---------------------------------------------------------------------------
// gemm2_mfma: out = sum_j prob_j * (K_j . W_j + bias_j).  64x64 tile, BK=32,
// 512 blocks (2/CU). Softmax over j computed in prologue from sj+kdd.
// prob folded via dual accumulators (j = kk>>6 constant per BK tile).
// ---------------------------------------------------------------------------
__global__ __launch_bounds__(256) void gemm2_mfma(const ushort_t* __restrict__ Ks,
                                                  const ushort_t* __restrict__ Wt,
                                                  const float* __restrict__ sj,
                                                  const float* __restrict__ kdd,
                                                  const float* __restrict__ bias,
                                                  float* __restrict__ out) {
    __shared__ short As[64 * 32];            // 4 KB
    __shared__ short Bs[64 * 32];            // 4 KB
    __shared__ float probS[64 * 17];         // 4.25 KB
    __shared__ float biasS[16 * 64];         // 4 KB
    __shared__ float kddS[J_SZ];
    const int b0 = blockIdx.x * 64;
    const int u0 = blockIdx.y * 64;
    const int tid = threadIdx.x;
    const int wid = tid >> 6, lane = tid & 63;
    const int wm = wid >> 1, wn = wid & 1;
    const int lcol = lane & 15, quad = lane >> 4;

    if (tid < J_SZ) kddS[tid] = kdd[tid];
    {
        int rowj = tid >> 4, c4 = (tid & 15) << 2;
        *(float4*)&biasS[rowj * 64 + c4] = *(const float4*)&bias[(size_t)rowj * U_SZ + u0 + c4];
    }
    __syncthreads();
    if (tid < 64) {
        int b = b0 + tid;
        float lg[J_SZ], mx = -1e30f;
#pragma unroll
        for (int j = 0; j < J_SZ; ++j) {
            lg[j] = 2.f * sj[(size_t)b * J_SZ + j] - kddS[j] - 1.f;
            mx = fmaxf(mx, lg[j]);
        }
        float ssum = 0.f;
#pragma unroll
        for (int j = 0; j < J_SZ; ++j) { lg[j] = __expf(lg[j] - mx); ssum += lg[j]; }
        float inv = 1.f / ssum;
#pragma unroll
        for (int j = 0; j < J_SZ; ++j) probS[tid * 17 + j] = lg[j] * inv;
    }
    __syncthreads();

    f32x4 acc_tot[2][2], acc_cur[2][2];
    for (int i = 0; i < 2; ++i)
        for (int n = 0; n < 2; ++n) {
            acc_tot[i][n] = (f32x4){0.f, 0.f, 0.f, 0.f};
            acc_cur[i][n] = (f32x4){0.f, 0.f, 0.f, 0.f};
        }

    for (int jb = 0; jb < J_SZ; ++jb) {
        float pf[2][4];
#pragma unroll
        for (int i = 0; i < 2; ++i)
#pragma unroll
            for (int r = 0; r < 4; ++r)
                pf[i][r] = probS[(wm * 32 + i * 16 + quad * 4 + r) * 17 + jb];
#pragma unroll
        for (int s = 0; s < 2; ++s) {
            int kk = jb * 64 + s * 32;
            {
                int row = tid >> 2, seg = tid & 3;
                gload_lds16(Ks + (size_t)(b0 + row) * P_SZ + kk + seg * 8, &As[tid * 8]);
                gload_lds16(Wt + (size_t)(u0 + row) * P_SZ + kk + seg * 8, &Bs[tid * 8]);
            }
            __syncthreads();
            bf16x8 ar[2], br[2];
#pragma unroll
            for (int i = 0; i < 2; ++i)
                ar[i] = *(const bf16x8*)&As[(wm * 32 + i * 16 + lcol) * 32 + quad * 8];
#pragma unroll
            for (int n = 0; n < 2; ++n)
                br[n] = *(const bf16x8*)&Bs[(wn * 32 + n * 16 + lcol) * 32 + quad * 8];
#pragma unroll
            for (int i = 0; i < 2; ++i)
#pragma unroll
                for (int n = 0; n < 2; ++n)
                    acc_cur[i][n] = __builtin_amdgcn_mfma_f32_16x16x32_bf16(ar[i], br[n], acc_cur[i][n], 0, 0, 0);
            __syncthreads();
        }
        // fold this domain's partial with its probability
#pragma unroll
        for (int i = 0; i < 2; ++i)
#pragma unroll
            for (int n = 0; n < 2; ++n) {
#pragma unroll
                for (int r = 0; r < 4; ++r)
                    acc_tot[i][n][r] += pf[i][r] * acc_cur[i][n][r];
                acc_cur[i][n] = (f32x4){0.f, 0.f, 0.f, 0.f};
            }
    }

    // ---- epilogue: + sum_j prob*bias ----
    float bv[2][J_SZ];
#pragma unroll
    for (int n = 0; n < 2; ++n) {
        int col = wn * 32 + n * 16 + lcol;
#pragma unroll
        for (int j = 0; j < J_SZ; ++j) bv[n][j] = biasS[j * 64 + col];
    }
#pragma unroll
    for (int i = 0; i < 2; ++i) {
#pragma unroll
        for (int r = 0; r < 4; ++r) {
            int row = wm * 32 + i * 16 + quad * 4 + r;
            int b = b0 + row;
#pragma unroll
            for (int n = 0; n < 2; ++n) {
                float a = acc_tot[i][n][r];
#pragma unroll
                for (int j = 0; j < J_SZ; ++j) a += probS[row * 17 + j] * bv[n][j];
                out[(size_t)b * U_SZ + u0 + wn * 32 + n * 16 + lcol] = a;
            }
        }
    }
}

// ---------------------------------------------------------------------------
extern "C" void kernel_launch(void* const* d_in, const int* in_sizes, int n_in,
                              void* d_out, int out_size, void* d_ws, size_t ws_size,
                              hipStream_t stream) {
    const float* h    = (const float*)d_in[0];   // [B,F]
    const float* dom  = (const float*)d_in[1];   // [J,M,F]
    const float* W    = (const float*)d_in[2];   // [J,M,U]
    const float* bias = (const float*)d_in[3];   // [J,U]
    float* out = (float*)d_out;                  // [B,U]

    char* ws = (char*)d_ws;
    ushort_t* hbf   = (ushort_t*)ws;  ws += (size_t)B_SZ * F_SZ * 2;            // 4 MB
    ushort_t* dombf = (ushort_t*)ws;  ws += (size_t)P_SZ * F_SZ * 2;            // 1 MB
    ushort_t* Wt    = (ushort_t*)ws;  ws += (size_t)U_SZ * P_SZ * 2;            // 1 MB
    ushort_t* Kbf   = (ushort_t*)ws;  ws += (size_t)B_SZ * P_SZ * 2;            // 8 MB
    float* h2    = (float*)ws;  ws += B_SZ * 4;
    float* d2    = (float*)ws;  ws += P_SZ * 4;
    float* kdd   = (float*)ws;  ws += 64;
    float* sj    = (float*)ws;  ws += (size_t)B_SZ * J_SZ * 4;
    float* Gpart = (float*)ws;  ws += (size_t)4 * J_SZ * M_SZ * M_SZ * 4;       // 1 MB

    prep_kernel<<<1472, 256, 0, stream>>>(h, dom, W, hbf, dombf, Wt, h2, d2, Gpart);
    kdd_reduce<<<J_SZ, 256, 0, stream>>>(Gpart, d2, kdd);
    gemm1_mfma<<<dim3(B_SZ / 64, P_SZ / 128), 256, 0, stream>>>(hbf, dombf, h2, d2, Kbf, sj);
    gemm2_mfma<<<dim3(B_SZ / 64, U_SZ / 64), 256, 0, stream>>>(Kbf, Wt, sj, kdd, bias, out);
}